// Round 5
// baseline (347.129 us; speedup 1.0000x reference)
//
#include <hip/hip_runtime.h>
#include <hip/hip_bf16.h>
#include <cstdint>

#define TSEQ 4096
#define CDIM 2048
#define HDIM 128

typedef short bf8v __attribute__((ext_vector_type(8)));  // 8 bf16 raw bits (4 VGPRs)
typedef float f4v  __attribute__((ext_vector_type(4)));

__device__ __forceinline__ unsigned short f2b(float f) {
  union { float f; unsigned u; } v; v.f = f;
  unsigned u = v.u;
  return (unsigned short)((u + 0x7fffu + ((u >> 16) & 1u)) >> 16);  // RNE
}

__device__ __forceinline__ f4v mfma16(bf8v a, bf8v b, f4v c) {
  return __builtin_amdgcn_mfma_f32_16x16x32_bf16(a, b, c, 0, 0, 0);
}

// ---------------- Kernel 1: Wq|Wk|Wv fp32 -> Wcat bf16 [384][2048] ----------------
__global__ void wcat_kernel(const float* __restrict__ Wq, const float* __restrict__ Wk,
                            const float* __restrict__ Wv, unsigned short* __restrict__ Wcat) {
  int e = (blockIdx.x * 256 + threadIdx.x) * 4;
  int n = e >> 11;
  int k = e & 2047;
  const float* src;
  if (n < 128)      src = Wq + (size_t)n * CDIM + k;
  else if (n < 256) src = Wk + (size_t)(n - 128) * CDIM + k;
  else              src = Wv + (size_t)(n - 256) * CDIM + k;
  float4 f = *(const float4*)src;
  ushort4 o;
  o.x = f2b(f.x); o.y = f2b(f.y); o.z = f2b(f.z); o.w = f2b(f.w);
  *(ushort4*)(Wcat + e) = o;
}

// ---------------- Kernel 2: proj GEMM v3 — 64x128 tile, 512 thr (8 waves), dbuf ----
// A: idx fp32 [16384][2048]; B: Wcat bf16, y selects q/k/v 128-col slice.
// Wave grid 2x4, 32x32 per wave. Epilogue writes frag-major QB/KA/VB
// (VB gets a 9th "ones" h-tile for row-sums).
__global__ __launch_bounds__(512, 6) void proj_gemm(const float* __restrict__ A,
                                                    const unsigned short* __restrict__ Bw,
                                                    unsigned short* __restrict__ QB,
                                                    unsigned short* __restrict__ KA,
                                                    unsigned short* __restrict__ VB) {
  __shared__ union {
    struct { unsigned short As[2][64][40]; unsigned short Bs[2][128][40]; } st;  // 30.7 KB
    unsigned short Ct[64][132];                                                  // 16.9 KB
  } sm;
  const int m0 = blockIdx.x * 64;
  const int y  = blockIdx.y;          // 0=q, 1=k, 2=v
  const int n0 = y * 128;
  const int tid = threadIdx.x;
  const int lane = tid & 63;
  const int w = tid >> 6;             // 8 waves
  const int wm = (w & 1) * 32, wn = (w >> 1) * 32;
  const int llo = lane & 15, lhi = lane >> 4;

  f4v acc[2][2];
#pragma unroll
  for (int i = 0; i < 2; ++i)
#pragma unroll
    for (int j = 0; j < 2; ++j) acc[i][j] = (f4v){0.f, 0.f, 0.f, 0.f};

  const int arow = tid >> 3, acol = (tid & 7) * 4;   // 64 rows x 32 cols fp32
  const int brow = tid >> 2, bcol = (tid & 3) * 8;   // 128 rows x 32 cols bf16
  const float* aptr = A + (size_t)(m0 + arow) * CDIM + acol;
  const unsigned short* bptr = Bw + (size_t)(n0 + brow) * CDIM + bcol;

  float4 fa = *(const float4*)(aptr);
  uint4  ub = *(const uint4*)(bptr);
  {
    ushort4 o;
    o.x = f2b(fa.x); o.y = f2b(fa.y); o.z = f2b(fa.z); o.w = f2b(fa.w);
    *(ushort4*)&sm.st.As[0][arow][acol] = o;
    *(uint4*)&sm.st.Bs[0][brow][bcol]   = ub;
  }

  for (int it = 0; it < 64; ++it) {
    const int cur = it & 1;
    __syncthreads();  // buf[cur] visible
    if (it < 63) {    // issue next-step global loads; consumed at loop end
      fa = *(const float4*)(aptr + (it + 1) * 32);
      ub = *(const uint4*)(bptr + (it + 1) * 32);
    }
    bf8v af[2], bfr[2];
    af[0]  = *(const bf8v*)&sm.st.As[cur][wm + llo][lhi * 8];
    af[1]  = *(const bf8v*)&sm.st.As[cur][wm + 16 + llo][lhi * 8];
    bfr[0] = *(const bf8v*)&sm.st.Bs[cur][wn + llo][lhi * 8];
    bfr[1] = *(const bf8v*)&sm.st.Bs[cur][wn + 16 + llo][lhi * 8];
#pragma unroll
    for (int i = 0; i < 2; ++i)
#pragma unroll
      for (int j = 0; j < 2; ++j) acc[i][j] = mfma16(af[i], bfr[j], acc[i][j]);
    if (it < 63) {
      ushort4 o;
      o.x = f2b(fa.x); o.y = f2b(fa.y); o.z = f2b(fa.z); o.w = f2b(fa.w);
      int nxt = cur ^ 1;
      *(ushort4*)&sm.st.As[nxt][arow][acol] = o;
      *(uint4*)&sm.st.Bs[nxt][brow][bcol]   = ub;
    }
  }
  __syncthreads();  // done reading staging; union flips to Ct
#pragma unroll
  for (int i = 0; i < 2; ++i)
#pragma unroll
    for (int j = 0; j < 2; ++j)
#pragma unroll
      for (int r = 0; r < 4; ++r)
        sm.Ct[wm + i * 16 + lhi * 4 + r][wn + j * 16 + llo] = f2b(acc[i][j][r]);
  __syncthreads();
  if (y < 2) {
    unsigned short* dst = (y == 0) ? QB : KA;
    const size_t base16 = (size_t)(m0 >> 4);  // global 16-row tile index
#pragma unroll
    for (int p = 0; p < 2; ++p) {
      int g = p * 512 + tid;                  // 4 t16 * 4 kk * 64 = 1024
      int t16l = g >> 8, kk = (g >> 6) & 3, ln = g & 63;
      int lo = ln & 15, hi = ln >> 4;
      bf8v v = *(const bf8v*)&sm.Ct[t16l * 16 + lo][kk * 32 + hi * 8];
      *(bf8v*)(dst + (((base16 + t16l) * 4 + kk) * 64 + ln) * 8) = v;
    }
  } else {
    const size_t base32 = (size_t)(m0 >> 5);  // global 32-row chunk index
#pragma unroll
    for (int p = 0; p < 3; ++p) {
      int g = p * 512 + tid;                  // 2 jbl * 9 ht * 64 = 1152
      if (g < 1152) {
        int jbl = g / 576;
        int ht  = (g % 576) >> 6;
        int ln  = g & 63;
        int lo = ln & 15, hi = ln >> 4;
        bf8v v;
        if (ht == 8) {
#pragma unroll
          for (int e = 0; e < 8; ++e) v[e] = (lo == 0) ? (short)0x3F80 : (short)0;
        } else {
#pragma unroll
          for (int e = 0; e < 8; ++e) v[e] = (short)sm.Ct[jbl * 32 + hi * 8 + e][ht * 16 + lo];
        }
        *(bf8v*)(VB + (((base32 + jbl) * 9 + ht) * 512 + (size_t)ln * 8)) = v;
      }
    }
  }
}

// ---------------- Kernel 3: flash attention v5 — 8 waves/block, jt split 8 ways -----
// No cross-lane ops in the loop (fixed m=0, row-sum via ones-column in VB).
// 512 thr = 8 waves; 4 blocks/CU -> 32 waves/CU (100% static occupancy).
__global__ __launch_bounds__(512, 8) void attn5(const unsigned short* __restrict__ QB,
                                                const unsigned short* __restrict__ KA,
                                                const unsigned short* __restrict__ VB,
                                                float* __restrict__ out) {
  __shared__ union SM {
    unsigned short Ps[8][16][68];                       // wave-private P staging, 17.4 KB
    struct { float Om[8][16][66]; float Lm[8][16]; } mg;  // 34.3 KB
  } sm;
  const int x = blockIdx.x;
  // snake balance: {x, x+256, x+512, x+768} (round-robin co-residents) sum ~const
  const int b = x & 3;
  const int u = x >> 2;
  const int g = u >> 6, r0 = u & 63;
  const int s = (g & 1) ? (g * 64 + 63 - r0) : (g * 64 + r0);
  const int lastjt = s >> 2;
  const int tid = threadIdx.x;
  const int w = tid >> 6, lane = tid & 63;   // 8 waves
  const int llo = lane & 15, lhi = lane >> 4;
  const float scale = 0.022097086912079608f;  // 2048^-0.5

  bf8v aK[4];
  {
    const unsigned short* kp = KA + (size_t)(b * 256 + s) * 2048;
#pragma unroll
    for (int kk = 0; kk < 4; ++kk) aK[kk] = *(const bf8v*)(kp + (kk * 64 + lane) * 8);
  }

  f4v Oacc[9];
#pragma unroll
  for (int nt = 0; nt < 9; ++nt) Oacc[nt] = (f4v){0.f, 0.f, 0.f, 0.f};

  for (int jt = w; jt <= lastjt; jt += 8) {
    const unsigned short* qp = QB + (size_t)(b * 256 + jt * 4) * 2048;
    // S = K.Q^T (16 x 64), P = exp(S*scale) straight into LDS (A-layout)
#pragma unroll
    for (int ct = 0; ct < 4; ++ct) {
      f4v acc = (f4v){0.f, 0.f, 0.f, 0.f};
#pragma unroll
      for (int kk = 0; kk < 4; ++kk) {
        bf8v bq = *(const bf8v*)(qp + ((ct * 4 + kk) * 64 + lane) * 8);
        acc = mfma16(aK[kk], bq, acc);
      }
#pragma unroll
      for (int r = 0; r < 4; ++r) {
        float sv = acc[r];
        if (jt == lastjt) {
          int j = jt * 64 + ct * 16 + llo;
          int i = s * 16 + lhi * 4 + r;
          if (j > i) sv = -3.0e38f;
        }
        sm.Ps[w][lhi * 4 + r][ct * 16 + llo] = f2b(__expf(sv * scale));
      }
    }
    bf8v aP[2];
    aP[0] = *(const bf8v*)&sm.Ps[w][llo][lhi * 8];
    aP[1] = *(const bf8v*)&sm.Ps[w][llo][32 + lhi * 8];
    // O += P @ [V | ones]  (nt=8 accumulates the row sum in col lane 0)
    const unsigned short* vp = VB + (size_t)(b * 128 + jt * 2) * 4608;  // 9 ht * 512
#pragma unroll
    for (int nt = 0; nt < 9; ++nt) {
      f4v o = Oacc[nt];
#pragma unroll
      for (int kk = 0; kk < 2; ++kk) {
        bf8v bv = *(const bf8v*)(vp + kk * 4608 + nt * 512 + (size_t)lane * 8);
        o = mfma16(aP[kk], bv, o);
      }
      Oacc[nt] = o;
    }
  }

  // merge the 8 waves' partials (plain sums; two 64-col halves)
#pragma unroll
  for (int half = 0; half < 2; ++half) {
    __syncthreads();
#pragma unroll
    for (int nt = 0; nt < 4; ++nt)
#pragma unroll
      for (int r = 0; r < 4; ++r)
        sm.mg.Om[w][lhi * 4 + r][nt * 16 + llo] = Oacc[half * 4 + nt][r];
    if (half == 0 && llo == 0) {
#pragma unroll
      for (int r = 0; r < 4; ++r) sm.mg.Lm[w][lhi * 4 + r] = Oacc[8][r];
    }
    __syncthreads();
    {
      int row = tid >> 5, c0 = (tid & 31) * 2;   // 16 rows x 64 cols / 512 thr = 2 cols
      float L = 0.f;
#pragma unroll
      for (int ww = 0; ww < 8; ++ww) L += sm.mg.Lm[ww][row];
      float inv = 1.0f / L;
      float o0 = 0.f, o1 = 0.f;
#pragma unroll
      for (int ww = 0; ww < 8; ++ww) {
        o0 += sm.mg.Om[ww][row][c0];
        o1 += sm.mg.Om[ww][row][c0 + 1];
      }
      float* op = out + (size_t)(b * TSEQ + s * 16 + row) * HDIM + half * 64 + c0;
      op[0] = o0 * inv;
      op[1] = o1 * inv;
    }
  }
}

extern "C" void kernel_launch(void* const* d_in, const int* in_sizes, int n_in,
                              void* d_out, int out_size, void* d_ws, size_t ws_size,
                              hipStream_t stream) {
  const float* idx = (const float*)d_in[0];
  const float* Wq  = (const float*)d_in[1];
  const float* Wk  = (const float*)d_in[2];
  const float* Wv  = (const float*)d_in[3];
  float* out = (float*)d_out;
  char* ws = (char*)d_ws;
  unsigned short* Wcat = (unsigned short*)ws;                        // 1.57 MB
  unsigned short* QB   = (unsigned short*)(ws + ((size_t)2  << 20)); // 4.2 MB
  unsigned short* KA   = (unsigned short*)(ws + ((size_t)7  << 20)); // 4.2 MB
  unsigned short* VB   = (unsigned short*)(ws + ((size_t)12 << 20)); // 4.72 MB

  wcat_kernel<<<768, 256, 0, stream>>>(Wq, Wk, Wv, Wcat);
  proj_gemm<<<dim3(256, 3), 512, 0, stream>>>(idx, Wcat, QB, KA, VB);
  attn5<<<1024, 512, 0, stream>>>(QB, KA, VB, out);
}

// Round 6
// 290.446 us; speedup vs baseline: 1.1952x; 1.1952x over previous
//
#include <hip/hip_runtime.h>
#include <hip/hip_bf16.h>
#include <cstdint>

#define TSEQ 4096
#define CDIM 2048
#define HDIM 128

typedef short bf8v __attribute__((ext_vector_type(8)));  // 8 bf16 raw bits (4 VGPRs)
typedef float f4v  __attribute__((ext_vector_type(4)));

__device__ __forceinline__ unsigned short f2b(float f) {
  union { float f; unsigned u; } v; v.f = f;
  unsigned u = v.u;
  return (unsigned short)((u + 0x7fffu + ((u >> 16) & 1u)) >> 16);  // RNE
}

__device__ __forceinline__ f4v mfma16(bf8v a, bf8v b, f4v c) {
  return __builtin_amdgcn_mfma_f32_16x16x32_bf16(a, b, c, 0, 0, 0);
}

// ---------------- Kernel 1: Wq|Wk|Wv fp32 -> Wcat bf16 [384][2048] ----------------
__global__ void wcat_kernel(const float* __restrict__ Wq, const float* __restrict__ Wk,
                            const float* __restrict__ Wv, unsigned short* __restrict__ Wcat) {
  int e = (blockIdx.x * 256 + threadIdx.x) * 4;
  int n = e >> 11;
  int k = e & 2047;
  const float* src;
  if (n < 128)      src = Wq + (size_t)n * CDIM + k;
  else if (n < 256) src = Wk + (size_t)(n - 128) * CDIM + k;
  else              src = Wv + (size_t)(n - 256) * CDIM + k;
  float4 f = *(const float4*)src;
  ushort4 o;
  o.x = f2b(f.x); o.y = f2b(f.y); o.z = f2b(f.z); o.w = f2b(f.w);
  *(ushort4*)(Wcat + e) = o;
}

// ---------------- Kernel 2: proj GEMM v3 — 64x128 tile, 512 thr (8 waves), dbuf ----
// (unchanged from R5 — ~90 µs, not the current bottleneck)
__global__ __launch_bounds__(512, 6) void proj_gemm(const float* __restrict__ A,
                                                    const unsigned short* __restrict__ Bw,
                                                    unsigned short* __restrict__ QB,
                                                    unsigned short* __restrict__ KA,
                                                    unsigned short* __restrict__ VB) {
  __shared__ union {
    struct { unsigned short As[2][64][40]; unsigned short Bs[2][128][40]; } st;
    unsigned short Ct[64][132];
  } sm;
  const int m0 = blockIdx.x * 64;
  const int y  = blockIdx.y;          // 0=q, 1=k, 2=v
  const int n0 = y * 128;
  const int tid = threadIdx.x;
  const int lane = tid & 63;
  const int w = tid >> 6;
  const int wm = (w & 1) * 32, wn = (w >> 1) * 32;
  const int llo = lane & 15, lhi = lane >> 4;

  f4v acc[2][2];
#pragma unroll
  for (int i = 0; i < 2; ++i)
#pragma unroll
    for (int j = 0; j < 2; ++j) acc[i][j] = (f4v){0.f, 0.f, 0.f, 0.f};

  const int arow = tid >> 3, acol = (tid & 7) * 4;
  const int brow = tid >> 2, bcol = (tid & 3) * 8;
  const float* aptr = A + (size_t)(m0 + arow) * CDIM + acol;
  const unsigned short* bptr = Bw + (size_t)(n0 + brow) * CDIM + bcol;

  float4 fa = *(const float4*)(aptr);
  uint4  ub = *(const uint4*)(bptr);
  {
    ushort4 o;
    o.x = f2b(fa.x); o.y = f2b(fa.y); o.z = f2b(fa.z); o.w = f2b(fa.w);
    *(ushort4*)&sm.st.As[0][arow][acol] = o;
    *(uint4*)&sm.st.Bs[0][brow][bcol]   = ub;
  }

  for (int it = 0; it < 64; ++it) {
    const int cur = it & 1;
    __syncthreads();
    if (it < 63) {
      fa = *(const float4*)(aptr + (it + 1) * 32);
      ub = *(const uint4*)(bptr + (it + 1) * 32);
    }
    bf8v af[2], bfr[2];
    af[0]  = *(const bf8v*)&sm.st.As[cur][wm + llo][lhi * 8];
    af[1]  = *(const bf8v*)&sm.st.As[cur][wm + 16 + llo][lhi * 8];
    bfr[0] = *(const bf8v*)&sm.st.Bs[cur][wn + llo][lhi * 8];
    bfr[1] = *(const bf8v*)&sm.st.Bs[cur][wn + 16 + llo][lhi * 8];
#pragma unroll
    for (int i = 0; i < 2; ++i)
#pragma unroll
      for (int j = 0; j < 2; ++j) acc[i][j] = mfma16(af[i], bfr[j], acc[i][j]);
    if (it < 63) {
      ushort4 o;
      o.x = f2b(fa.x); o.y = f2b(fa.y); o.z = f2b(fa.z); o.w = f2b(fa.w);
      int nxt = cur ^ 1;
      *(ushort4*)&sm.st.As[nxt][arow][acol] = o;
      *(uint4*)&sm.st.Bs[nxt][brow][bcol]   = ub;
    }
  }
  __syncthreads();
#pragma unroll
  for (int i = 0; i < 2; ++i)
#pragma unroll
    for (int j = 0; j < 2; ++j)
#pragma unroll
      for (int r = 0; r < 4; ++r)
        sm.Ct[wm + i * 16 + lhi * 4 + r][wn + j * 16 + llo] = f2b(acc[i][j][r]);
  __syncthreads();
  if (y < 2) {
    unsigned short* dst = (y == 0) ? QB : KA;
    const size_t base16 = (size_t)(m0 >> 4);
#pragma unroll
    for (int p = 0; p < 2; ++p) {
      int g = p * 512 + tid;
      int t16l = g >> 8, kk = (g >> 6) & 3, ln = g & 63;
      int lo = ln & 15, hi = ln >> 4;
      bf8v v = *(const bf8v*)&sm.Ct[t16l * 16 + lo][kk * 32 + hi * 8];
      *(bf8v*)(dst + (((base16 + t16l) * 4 + kk) * 64 + ln) * 8) = v;
    }
  } else {
    const size_t base32 = (size_t)(m0 >> 5);
#pragma unroll
    for (int p = 0; p < 3; ++p) {
      int g = p * 512 + tid;
      if (g < 1152) {
        int jbl = g / 576;
        int ht  = (g % 576) >> 6;
        int ln  = g & 63;
        int lo = ln & 15, hi = ln >> 4;
        bf8v v;
        if (ht == 8) {
#pragma unroll
          for (int e = 0; e < 8; ++e) v[e] = (lo == 0) ? (short)0x3F80 : (short)0;
        } else {
#pragma unroll
          for (int e = 0; e < 8; ++e) v[e] = (short)sm.Ct[jbl * 32 + hi * 8 + e][ht * 16 + lo];
        }
        *(bf8v*)(VB + (((base32 + jbl) * 9 + ht) * 512 + (size_t)ln * 8)) = v;
      }
    }
  }
}

// ---------------- Kernel 3: flash attention v6 — software-pipelined, no spills -----
// 256 thr / 4 waves, (256,4) -> 128 VGPR cap (attn5's (512,8)=64 cap spilled: 225 MB
// scratch writes). 2-stage pipeline: S(t+1)/exp/P-write overlaps PV(t); P LDS is
// double-buffered per wave; no barriers or cross-lane ops in the loop.
__global__ __launch_bounds__(256, 4) void attn6(const unsigned short* __restrict__ QB,
                                                const unsigned short* __restrict__ KA,
                                                const unsigned short* __restrict__ VB,
                                                float* __restrict__ out) {
  __shared__ union SM {
    unsigned short Ps[4][2][16][68];                      // [wave][buf][row][col] 17.4 KB
    struct { float Om[4][16][68]; float Lm[4][16]; } mg;  // 17.7 KB
  } sm;
  const int x = blockIdx.x;
  // snake balance: {x, x+256, x+512, x+768} (round-robin co-residents) sum ~const
  const int b = x & 3;
  const int u = x >> 2;
  const int g = u >> 6, r0 = u & 63;
  const int s = (g & 1) ? (g * 64 + 63 - r0) : (g * 64 + r0);
  const int lastjt = s >> 2;
  const int tid = threadIdx.x;
  const int w = tid >> 6, lane = tid & 63;
  const int llo = lane & 15, lhi = lane >> 4;
  const float scale = 0.022097086912079608f;  // 2048^-0.5

  bf8v aK[4];
  {
    const unsigned short* kp = KA + (size_t)(b * 256 + s) * 2048;
#pragma unroll
    for (int kk = 0; kk < 4; ++kk) aK[kk] = *(const bf8v*)(kp + (kk * 64 + lane) * 8);
  }

  f4v Oacc[9];
#pragma unroll
  for (int nt = 0; nt < 9; ++nt) Oacc[nt] = (f4v){0.f, 0.f, 0.f, 0.f};

  // S = K.Q^T (16x64) -> P = exp(S*scale) -> LDS buf (A-layout), for tile jtS
  auto computeS = [&](int jtS, int buf) {
    const unsigned short* qp = QB + (size_t)(b * 256 + jtS * 4) * 2048;
#pragma unroll
    for (int ct = 0; ct < 4; ++ct) {
      f4v acc = (f4v){0.f, 0.f, 0.f, 0.f};
#pragma unroll
      for (int kk = 0; kk < 4; ++kk) {
        bf8v bq = *(const bf8v*)(qp + ((ct * 4 + kk) * 64 + lane) * 8);
        acc = mfma16(aK[kk], bq, acc);
      }
#pragma unroll
      for (int r = 0; r < 4; ++r) {
        float sv = acc[r];
        if (jtS == lastjt) {
          int j = jtS * 64 + ct * 16 + llo;
          int i = s * 16 + lhi * 4 + r;
          if (j > i) sv = -3.0e38f;
        }
        sm.Ps[w][buf][lhi * 4 + r][ct * 16 + llo] = f2b(__expf(sv * scale));
      }
    }
  };

  if (w <= lastjt) computeS(w, 0);
  int buf = 0;
  for (int jt = w; jt <= lastjt; jt += 4) {
    // read this tile's P frags from buf
    bf8v aP0 = *(const bf8v*)&sm.Ps[w][buf][llo][lhi * 8];
    bf8v aP1 = *(const bf8v*)&sm.Ps[w][buf][llo][32 + lhi * 8];
    // pipeline: next tile's S/exp/P-write overlaps this tile's PV below
    if (jt + 4 <= lastjt) computeS(jt + 4, buf ^ 1);
    // O += P @ [V | ones]  (nt=8 accumulates the row sum in col lane 0)
    const unsigned short* vp = VB + (size_t)(b * 128 + jt * 2) * 4608;  // 9 ht * 512
#pragma unroll
    for (int nt = 0; nt < 9; ++nt) {
      f4v o = Oacc[nt];
      o = mfma16(aP0, *(const bf8v*)(vp + nt * 512 + (size_t)lane * 8), o);
      o = mfma16(aP1, *(const bf8v*)(vp + 4608 + nt * 512 + (size_t)lane * 8), o);
      Oacc[nt] = o;
    }
    buf ^= 1;
  }

  // merge the 4 waves' partials (plain sums; two 64-col halves)
#pragma unroll
  for (int half = 0; half < 2; ++half) {
    __syncthreads();
#pragma unroll
    for (int nt = 0; nt < 4; ++nt)
#pragma unroll
      for (int r = 0; r < 4; ++r)
        sm.mg.Om[w][lhi * 4 + r][nt * 16 + llo] = Oacc[half * 4 + nt][r];
    if (half == 0 && llo == 0) {
#pragma unroll
      for (int r = 0; r < 4; ++r) sm.mg.Lm[w][lhi * 4 + r] = Oacc[8][r];
    }
    __syncthreads();
    {
      int row = tid >> 4, c0 = (tid & 15) * 4;
      float L = sm.mg.Lm[0][row] + sm.mg.Lm[1][row] + sm.mg.Lm[2][row] + sm.mg.Lm[3][row];
      float inv = 1.0f / L;
      float* op = out + (size_t)(b * TSEQ + s * 16 + row) * HDIM + half * 64 + c0;
#pragma unroll
      for (int e = 0; e < 4; ++e) {
        float o = sm.mg.Om[0][row][c0 + e] + sm.mg.Om[1][row][c0 + e] +
                  sm.mg.Om[2][row][c0 + e] + sm.mg.Om[3][row][c0 + e];
        op[e] = o * inv;
      }
    }
  }
}

extern "C" void kernel_launch(void* const* d_in, const int* in_sizes, int n_in,
                              void* d_out, int out_size, void* d_ws, size_t ws_size,
                              hipStream_t stream) {
  const float* idx = (const float*)d_in[0];
  const float* Wq  = (const float*)d_in[1];
  const float* Wk  = (const float*)d_in[2];
  const float* Wv  = (const float*)d_in[3];
  float* out = (float*)d_out;
  char* ws = (char*)d_ws;
  unsigned short* Wcat = (unsigned short*)ws;                        // 1.57 MB
  unsigned short* QB   = (unsigned short*)(ws + ((size_t)2  << 20)); // 4.2 MB
  unsigned short* KA   = (unsigned short*)(ws + ((size_t)7  << 20)); // 4.2 MB
  unsigned short* VB   = (unsigned short*)(ws + ((size_t)12 << 20)); // 4.72 MB

  wcat_kernel<<<768, 256, 0, stream>>>(Wq, Wk, Wv, Wcat);
  proj_gemm<<<dim3(256, 3), 512, 0, stream>>>(idx, Wcat, QB, KA, VB);
  attn6<<<1024, 256, 0, stream>>>(QB, KA, VB, out);
}